// Round 11
// baseline (64.932 us; speedup 1.0000x reference)
//
#include <hip/hip_runtime.h>

#define NB 64
#define NE 40000
#define DIM 200
#define NL 100
#define EBLK 32
#define NTHREADS 256
#define D4 50          // float4 per E row
#define L4 25          // float4 per num_lit row
#define LOG2E 1.4426950408889634f

#define WS_E1R 0       // bf16 [64][224] (e1*r): 28672 B (ONLY ws use)

// LDS arena byte offsets (lifetimes are phase-disjoint):
//   phase 1 : A [0,16384) + Bm [16384,24576)
//   scatter : scat [0,8448)           (after phase-1 reads done)
//   phase 2 : xsF [0,12800) + asw [12800,27136)  (after gather barrier)
#define A_OFF    0
#define BM_OFF   16384
#define SCAT_OFF 0
#define XS_OFF   0
#define ASW_OFF  12800
#define SMEM_BYTES 27136

typedef float f32x4 __attribute__((ext_vector_type(4)));
typedef short bf16x8 __attribute__((ext_vector_type(8)));
// SESSION RULE (r4/r5/r7/r8/r9): NO f32x2 packed arithmetic — every build
// using it failed with build-varying absmax 0.027-0.063. Scalar math only.

__device__ __forceinline__ unsigned int f2bf(float f) {
    unsigned int u = __float_as_uint(f);
    return (u + 0x7fffu + ((u >> 16) & 1u)) >> 16;  // RNE
}
__device__ __forceinline__ unsigned int packbf(float a, float b) {
    return f2bf(a) | (f2bf(b) << 16);
}

// ---------------- pre-kernel: bake bf16 e1*r into d_ws ----------------
__global__ void DistMult_prep_kernel(
    const int* __restrict__ e1_idx, const int* __restrict__ r_idx,
    const float* __restrict__ Ew, const float* __restrict__ Rw,
    unsigned char* __restrict__ ws)
{
    const int t = blockIdx.x * NTHREADS + threadIdx.x;  // grid 8*256
    unsigned int* e1r = (unsigned int*)(ws + WS_E1R);   // 112 uint per row
    const float4* E4 = (const float4*)Ew;
    const float4* R4 = (const float4*)Rw;

    for (int f = t; f < NB * 28; f += 8 * NTHREADS) {
        int b = f / 28, c = f % 28;
        uint4 st = {0u, 0u, 0u, 0u};
        if (c < 25) {
            float4 a0 = E4[(size_t)e1_idx[b] * D4 + 2 * c];
            float4 a1 = E4[(size_t)e1_idx[b] * D4 + 2 * c + 1];
            float4 r0 = R4[(size_t)r_idx[b] * D4 + 2 * c];
            float4 r1 = R4[(size_t)r_idx[b] * D4 + 2 * c + 1];
            st.x = packbf(a0.x * r0.x, a0.y * r0.y);
            st.y = packbf(a0.z * r0.z, a0.w * r0.w);
            st.z = packbf(a1.x * r1.x, a1.y * r1.y);
            st.w = packbf(a1.z * r1.z, a1.w * r1.w);
        }
        *(uint4*)(e1r + (size_t)b * 112 + c * 4) = st;
    }
}

// Per-warp asw staging: load quarter (ol4, nl4) operands into registers.
__device__ __forceinline__ bool asw_load(
    const float4* N4, const float4* C4, const float4* W4,
    const int* sIdxE, const int* sIdxR, int w, int L, int ol4, int nl4,
    float4& n0, float4& n1, float4& cc, float4& w0, float4& w1,
    int& pc4, int& pi0)
{
    pc4 = L & 7; pi0 = L >> 3;
    if (pc4 >= nl4) return false;
    int b0 = 16 * w + pi0, b1 = b0 + 8;
    n0 = N4[(size_t)sIdxE[b0] * L4 + ol4 + pc4];
    n1 = N4[(size_t)sIdxE[b1] * L4 + ol4 + pc4];
    cc = C4[ol4 + pc4];
    w0 = W4[(size_t)sIdxR[b0] * L4 + ol4 + pc4];
    w1 = W4[(size_t)sIdxR[b1] * L4 + ol4 + pc4];
    return true;
}

// Write staged quarter into warp-private asw buffer [28][8 pairs][as0,w0,as1,w1].
__device__ __forceinline__ void asw_write(
    float* aswW, const float* sS, int olq, int pc4, int pi0,
    const float4& n0, const float4& n1, const float4& cc,
    const float4& w0, const float4& w1)
{
    const float* n0f = (const float*)&n0;
    const float* n1f = (const float*)&n1;
    const float* ccf = (const float*)&cc;
    const float* w0f = (const float*)&w0;
    const float* w1f = (const float*)&w1;
    const int p0 = pi0 >> 1, h0 = pi0 & 1;  // row pi0; row pi0+8 -> pair+4, same half
    #pragma unroll
    for (int k = 0; k < 4; ++k) {
        int l = 4 * pc4 + k;
        float s = sS[olq + l];
        float2 v0; v0.x = (n0f[k] - ccf[k]) * s; v0.y = w0f[k];
        float2 v1; v1.x = (n1f[k] - ccf[k]) * s; v1.y = w1f[k];
        *(float2*)(aswW + (l * 8 + p0) * 4 + h0 * 2) = v0;
        *(float2*)(aswW + (l * 8 + p0 + 4) * 4 + h0 * 2) = v1;
    }
}

__global__ __launch_bounds__(NTHREADS, 5)
void DistMult_KBLN_79164837200204_kernel(
    const int* __restrict__ e1_idx, const int* __restrict__ r_idx,
    const float* __restrict__ Ew, const float* __restrict__ num_lit,
    const float* __restrict__ cvec, const float* __restrict__ var,
    const float* __restrict__ nfw,
    const unsigned char* __restrict__ ws, float* __restrict__ out)
{
    __shared__ __align__(16) char smem[SMEM_BYTES];
    __shared__ float sS[NL];
    __shared__ int sIdxE[NB], sIdxR[NB];

    const int t = threadIdx.x;
    // Bijective XCD-chunked swizzle (m204), nwg = 1250.
    const int nq = (NE / EBLK) >> 3, nr = (NE / EBLK) & 7;
    const int xcd = blockIdx.x & 7, sub = blockIdx.x >> 3;
    const int wg = (xcd < nr ? xcd * (nq + 1) : nr * (nq + 1) + (xcd - nr) * nq) + sub;
    const int e0 = wg * EBLK;

    const int L = t & 63, w = t >> 6;
    const int l15 = L & 15, lq = L >> 4;
    const int tx = t & 7, ty = t >> 3, tyl = L >> 3;

    if (t < NL) sS[t] = sqrtf(LOG2E / var[t]);
    if (t < NB) { sIdxE[t] = e1_idx[t]; sIdxR[t] = r_idx[t]; }

    // ======== layout probe (r6-verified): true (b,e) of each acc slot ========
    unsigned short* pA  = (unsigned short*)(smem + A_OFF);   // row stride 32
    unsigned short* pBm = (unsigned short*)(smem + BM_OFF);
    for (int i = t; i < 1024; i += NTHREADS) ((unsigned int*)pA)[i] = 0u;
    for (int i = t; i < 512;  i += NTHREADS) ((unsigned int*)pBm)[i] = 0u;
    __syncthreads();
    if (t < 64) {
        pA[t * 32]     = (unsigned short)f2bf(256.0f * t);
        pA[t * 32 + 1] = (unsigned short)f2bf(1.0f);
    } else if (t < 96) {
        int e = t - 64;
        pBm[e * 32]     = (unsigned short)f2bf(1.0f);
        pBm[e * 32 + 1] = (unsigned short)f2bf((float)e);
    }
    __syncthreads();
    int ib0[4], ib1[4];
    {
        bf16x8 afp = *(const bf16x8*)(pA + (16 * w + l15) * 32 + lq * 8);
        bf16x8 b0p = *(const bf16x8*)(pBm + l15 * 32 + lq * 8);
        bf16x8 b1p = *(const bf16x8*)(pBm + (16 + l15) * 32 + lq * 8);
        f32x4 z = {0.f, 0.f, 0.f, 0.f};
        f32x4 p0 = __builtin_amdgcn_mfma_f32_16x16x32_bf16(afp, b0p, z, 0, 0, 0);
        f32x4 p1 = __builtin_amdgcn_mfma_f32_16x16x32_bf16(afp, b1p, z, 0, 0, 0);
        #pragma unroll
        for (int r = 0; r < 4; ++r) { ib0[r] = (int)p0[r]; ib1[r] = (int)p1[r]; }
    }
    __syncthreads();

    f32x4 acc0 = {0.f, 0.f, 0.f, 0.f};
    f32x4 acc1 = {0.f, 0.f, 0.f, 0.f};

    const float4* E4 = (const float4*)Ew;
    const uint4* wsA = (const uint4*)(ws + WS_E1R);  // 28 uint4 per row

    // ============ phase 1: score_l via MFMA, 2 K-halves (128 / 96) ============
    #pragma unroll
    for (int h = 0; h < 2; ++h) {
        const int nc = h ? 12 : 16;
        for (int f = t; f < NB * nc; f += NTHREADS) {
            int b = f / nc, c = f % nc;
            uint4 v = wsA[(size_t)b * 28 + h * 16 + c];
            int off = (b * 256 + c * 16) ^ ((b & 7) << 4);
            *(uint4*)(smem + A_OFF + off) = v;
        }
        for (int f = t; f < EBLK * nc; f += NTHREADS) {
            int e = f / nc, c = f % nc;
            int dg = h * 128 + c * 8;
            uint4 st = {0u, 0u, 0u, 0u};
            if (dg <= DIM - 8) {
                float4 v0 = E4[(size_t)(e0 + e) * D4 + (dg >> 2)];
                float4 v1 = E4[(size_t)(e0 + e) * D4 + (dg >> 2) + 1];
                st.x = packbf(v0.x, v0.y);
                st.y = packbf(v0.z, v0.w);
                st.z = packbf(v1.x, v1.y);
                st.w = packbf(v1.z, v1.w);
            }
            int off = (e * 256 + c * 16) ^ ((e & 7) << 4);
            *(uint4*)(smem + BM_OFF + off) = st;
        }
        __syncthreads();

        const int nst = h ? 3 : 4;
        const int arow = 16 * w + l15;
        const int aswz = (arow & 7) << 4;
        const int bswz = (l15 & 7) << 4;
        #pragma unroll
        for (int s = 0; s < 4; ++s) {
            if (s < nst) {
                int kb = s * 64 + lq * 16;
                bf16x8 af = *(const bf16x8*)(smem + A_OFF + ((arow * 256 + kb) ^ aswz));
                bf16x8 b0 = *(const bf16x8*)(smem + BM_OFF + ((l15 * 256 + kb) ^ bswz));
                bf16x8 b1 = *(const bf16x8*)(smem + BM_OFF + (((16 + l15) * 256 + kb) ^ bswz));
                acc0 = __builtin_amdgcn_mfma_f32_16x16x32_bf16(af, b0, acc0, 0, 0, 0);
                acc1 = __builtin_amdgcn_mfma_f32_16x16x32_bf16(af, b1, acc1, 0, 0, 0);
            }
        }
        __syncthreads();
    }

    // ======== scatter acc via probed coords, gather at r3 map ========
    float* scat = (float*)(smem + SCAT_OFF);
    #pragma unroll
    for (int r = 0; r < 4; ++r) {
        scat[(ib0[r] >> 8) * 33 + (ib0[r] & 255)] = acc0[r];
        scat[(ib1[r] >> 8) * 33 + (ib1[r] & 255)] = acc1[r];
    }
    __syncthreads();

    float2 acc2[4];
    #pragma unroll
    for (int j = 0; j < 4; ++j) {
        acc2[j].x = scat[(2 * ty) * 33 + 4 * tx + j];
        acc2[j].y = scat[(2 * ty + 1) * 33 + 4 * tx + j];
    }
    __syncthreads();

    // ============ phase 2: barrier-free warp-private quarters ============
    const float4* N4 = (const float4*)num_lit;
    const float4* C4 = (const float4*)cvec;
    const float4* W4 = (const float4*)nfw;
    float* xsF  = (float*)(smem + XS_OFF);              // [100][32]
    float* aswW = (float*)(smem + ASW_OFF) + w * 896;   // warp-private [28][8][4]

    // prologue: issue q0 loads, stage xsF (all 100 l), write q0 asw
    float4 n0, n1, ccv, wv0, wv1; int pc4, pi0;
    bool pv = asw_load(N4, C4, W4, sIdxE, sIdxR, w, L, 0, 7,
                       n0, n1, ccv, wv0, wv1, pc4, pi0);
    for (int f = t; f < 32 * 32; f += NTHREADS) {
        int e = f >> 5, c4s = f & 31;
        if (c4s < L4) {
            float4 v = N4[(size_t)(e0 + e) * L4 + c4s];
            const float* vf = (const float*)&v;
            #pragma unroll
            for (int k = 0; k < 4; ++k)
                xsF[(4 * c4s + k) * 32 + e] = vf[k] * sS[4 * c4s + k];
        }
    }
    if (pv) asw_write(aswW, sS, 0, pc4, pi0, n0, n1, ccv, wv0, wv1);
    __syncthreads();   // the ONLY phase-2 block barrier (xsF ready)

    #pragma unroll
    for (int q = 0; q < 4; ++q) {
        const int nl = (q < 3) ? 28 : 16;
        const int ol = q * 28;
        // T14: issue next quarter's global loads before computing this one
        if (q < 3)
            pv = asw_load(N4, C4, W4, sIdxE, sIdxR, w, L,
                          (q + 1) * 7, (q + 1 < 3) ? 7 : 4,
                          n0, n1, ccv, wv0, wv1, pc4, pi0);
        #pragma unroll 4
        for (int l = 0; l < nl; ++l) {
            float4 xs = *(const float4*)(xsF + (ol + l) * 32 + 4 * tx);
            float4 aw = *(const float4*)(aswW + (l * 8 + tyl) * 4);
            float xj[4] = { xs.x, xs.y, xs.z, xs.w };
            #pragma unroll
            for (int j = 0; j < 4; ++j) {
                float m0 = aw.x - xj[j];
                float m1 = aw.z - xj[j];
                float p0 = __builtin_amdgcn_exp2f(-(m0 * m0));
                float p1 = __builtin_amdgcn_exp2f(-(m1 * m1));
                acc2[j].x = fmaf(p0, aw.y, acc2[j].x);
                acc2[j].y = fmaf(p1, aw.w, acc2[j].y);
            }
        }
        if (q < 3) {
            // drain this warp's asw reads, then overwrite with next quarter
            asm volatile("s_waitcnt lgkmcnt(0)" ::: "memory");
            if (pv) asw_write(aswW, sS, (q + 1) * 28, pc4, pi0,
                              n0, n1, ccv, wv0, wv1);
            asm volatile("s_waitcnt lgkmcnt(0)" ::: "memory");
        }
    }

    // ============ epilogue: sigmoid + float4 stores (r10 verbatim) ============
    {
        float4 o0, o1;
        float* p0 = (float*)&o0;
        float* p1 = (float*)&o1;
        #pragma unroll
        for (int j = 0; j < 4; ++j) {
            float ex0 = __builtin_amdgcn_exp2f(-LOG2E * acc2[j].x);
            float ex1 = __builtin_amdgcn_exp2f(-LOG2E * acc2[j].y);
            p0[j] = __builtin_amdgcn_rcpf(1.0f + ex0);
            p1[j] = __builtin_amdgcn_rcpf(1.0f + ex1);
        }
        size_t b0 = 2 * ty;
        *(float4*)&out[b0 * NE + e0 + 4 * tx] = o0;
        *(float4*)&out[(b0 + 1) * NE + e0 + 4 * tx] = o1;
    }
}

extern "C" void kernel_launch(void* const* d_in, const int* in_sizes, int n_in,
                              void* d_out, int out_size, void* d_ws, size_t ws_size,
                              hipStream_t stream) {
    const int*   e1_idx  = (const int*)d_in[0];
    const int*   r_idx   = (const int*)d_in[1];
    const float* Ew      = (const float*)d_in[2];
    const float* Rw      = (const float*)d_in[3];
    const float* num_lit = (const float*)d_in[4];
    const float* cvec    = (const float*)d_in[5];
    const float* var     = (const float*)d_in[6];
    const float* nfw     = (const float*)d_in[7];
    float* out = (float*)d_out;

    DistMult_prep_kernel<<<8, NTHREADS, 0, stream>>>(
        e1_idx, r_idx, Ew, Rw, (unsigned char*)d_ws);
    DistMult_KBLN_79164837200204_kernel<<<NE / EBLK, NTHREADS, 0, stream>>>(
        e1_idx, r_idx, Ew, num_lit, cvec, var, nfw,
        (const unsigned char*)d_ws, out);
}

// Round 12
// 55.221 us; speedup vs baseline: 1.1758x; 1.1758x over previous
//
#include <hip/hip_runtime.h>

#define NB 64
#define NE 40000
#define DIM 200
#define NL 100
#define EBLK 32
#define NTHREADS 256
#define D4 50          // float4 per E row
#define L4 25          // float4 per num_lit row
#define LOG2E 1.4426950408889634f

#define WS_E1R 0       // bf16 [64][224] (e1*r):             28672 B
#define WS_ASW 28672   // f32 [100][64][2] ({as,w} per b):    51200 B
                       // total ws use: 79872 B

// LDS arena (phase-disjoint lifetimes):
//   phase 1 : A [0,16384) + Bm [16384,24576)
//   scatter : scat [0,8448)
//   phase 2 : xsF [0,12800)
#define A_OFF    0
#define BM_OFF   16384
#define SCAT_OFF 0
#define XS_OFF   0
#define SMEM_BYTES 24576

typedef float f32x4 __attribute__((ext_vector_type(4)));
typedef short bf16x8 __attribute__((ext_vector_type(8)));
// SESSION RULE (r4/r5/r7/r8/r9): NO f32x2 packed arithmetic — every build
// using it failed with build-varying absmax 0.027-0.063. Scalar math only.

__device__ __forceinline__ unsigned int f2bf(float f) {
    unsigned int u = __float_as_uint(f);
    return (u + 0x7fffu + ((u >> 16) & 1u)) >> 16;  // RNE
}
__device__ __forceinline__ unsigned int packbf(float a, float b) {
    return f2bf(a) | (f2bf(b) << 16);
}

// ---------------- pre-kernel: bake e1*r (bf16) and asw (f32) into d_ws ----------------
__global__ void DistMult_prep_kernel(
    const int* __restrict__ e1_idx, const int* __restrict__ r_idx,
    const float* __restrict__ Ew, const float* __restrict__ Rw,
    const float* __restrict__ num_lit, const float* __restrict__ cvec,
    const float* __restrict__ var, const float* __restrict__ nfw,
    unsigned char* __restrict__ ws)
{
    const int t = blockIdx.x * NTHREADS + threadIdx.x;  // grid 8*256 = 2048
    unsigned int* e1r = (unsigned int*)(ws + WS_E1R);   // 112 uint per row
    const float4* E4 = (const float4*)Ew;
    const float4* R4 = (const float4*)Rw;

    // e1r bf16 [64][224]
    for (int f = t; f < NB * 28; f += 8 * NTHREADS) {
        int b = f / 28, c = f % 28;
        uint4 st = {0u, 0u, 0u, 0u};
        if (c < 25) {
            float4 a0 = E4[(size_t)e1_idx[b] * D4 + 2 * c];
            float4 a1 = E4[(size_t)e1_idx[b] * D4 + 2 * c + 1];
            float4 r0 = R4[(size_t)r_idx[b] * D4 + 2 * c];
            float4 r1 = R4[(size_t)r_idx[b] * D4 + 2 * c + 1];
            st.x = packbf(a0.x * r0.x, a0.y * r0.y);
            st.y = packbf(a0.z * r0.z, a0.w * r0.w);
            st.z = packbf(a1.x * r1.x, a1.y * r1.y);
            st.w = packbf(a1.z * r1.z, a1.w * r1.w);
        }
        *(uint4*)(e1r + (size_t)b * 112 + c * 4) = st;
    }

    // asw f32 [100][64][2]: as = (n_h - c)*s, w = nfw gather.
    // Same scalar ops/order as the r10 in-block staging -> bitwise identical.
    float2* asw = (float2*)(ws + WS_ASW);
    for (int f = t; f < NL * NB; f += 8 * NTHREADS) {
        int b = f & 63, l = f >> 6;
        float s = sqrtf(LOG2E / var[l]);
        float2 v;
        v.x = (num_lit[(size_t)e1_idx[b] * NL + l] - cvec[l]) * s;
        v.y = nfw[(size_t)r_idx[b] * NL + l];
        asw[f] = v;   // f == l*64 + b
    }
}

// ---------------- main kernel ----------------
// Phase 1: MFMA + layout probe + scatter (r6-verified bridge).
// Phase 2: single 100-l loop; per l one coalesced global float4 (asw pair,
// L2-resident, block-invariant) + one LDS b128 (xs). No quarter staging.
__global__ __launch_bounds__(NTHREADS, 6)
void DistMult_KBLN_79164837200204_kernel(
    const float* __restrict__ Ew, const float* __restrict__ num_lit,
    const float* __restrict__ var,
    const unsigned char* __restrict__ ws, float* __restrict__ out)
{
    __shared__ __align__(16) char smem[SMEM_BYTES];
    __shared__ float sS[NL];

    const int t = threadIdx.x;
    // Bijective XCD-chunked swizzle (m204), nwg = 1250.
    const int nq = (NE / EBLK) >> 3, nr = (NE / EBLK) & 7;
    const int xcd = blockIdx.x & 7, sub = blockIdx.x >> 3;
    const int wg = (xcd < nr ? xcd * (nq + 1) : nr * (nq + 1) + (xcd - nr) * nq) + sub;
    const int e0 = wg * EBLK;

    const int L = t & 63, w = t >> 6;
    const int l15 = L & 15, lq = L >> 4;
    const int tx = t & 7, ty = t >> 3;

    if (t < NL) sS[t] = sqrtf(LOG2E / var[t]);

    // ======== layout probe (r6-verified): true (b,e) of each acc slot ========
    unsigned short* pA  = (unsigned short*)(smem + A_OFF);   // row stride 32
    unsigned short* pBm = (unsigned short*)(smem + BM_OFF);
    for (int i = t; i < 1024; i += NTHREADS) ((unsigned int*)pA)[i] = 0u;
    for (int i = t; i < 512;  i += NTHREADS) ((unsigned int*)pBm)[i] = 0u;
    __syncthreads();
    if (t < 64) {
        pA[t * 32]     = (unsigned short)f2bf(256.0f * t);
        pA[t * 32 + 1] = (unsigned short)f2bf(1.0f);
    } else if (t < 96) {
        int e = t - 64;
        pBm[e * 32]     = (unsigned short)f2bf(1.0f);
        pBm[e * 32 + 1] = (unsigned short)f2bf((float)e);
    }
    __syncthreads();
    int ib0[4], ib1[4];
    {
        bf16x8 afp = *(const bf16x8*)(pA + (16 * w + l15) * 32 + lq * 8);
        bf16x8 b0p = *(const bf16x8*)(pBm + l15 * 32 + lq * 8);
        bf16x8 b1p = *(const bf16x8*)(pBm + (16 + l15) * 32 + lq * 8);
        f32x4 z = {0.f, 0.f, 0.f, 0.f};
        f32x4 p0 = __builtin_amdgcn_mfma_f32_16x16x32_bf16(afp, b0p, z, 0, 0, 0);
        f32x4 p1 = __builtin_amdgcn_mfma_f32_16x16x32_bf16(afp, b1p, z, 0, 0, 0);
        #pragma unroll
        for (int r = 0; r < 4; ++r) { ib0[r] = (int)p0[r]; ib1[r] = (int)p1[r]; }
    }
    __syncthreads();

    f32x4 acc0 = {0.f, 0.f, 0.f, 0.f};
    f32x4 acc1 = {0.f, 0.f, 0.f, 0.f};

    const float4* E4 = (const float4*)Ew;
    const uint4* wsA = (const uint4*)(ws + WS_E1R);  // 28 uint4 per row

    // ============ phase 1: score_l via MFMA, 2 K-halves (128 / 96) ============
    #pragma unroll
    for (int h = 0; h < 2; ++h) {
        const int nc = h ? 12 : 16;
        for (int f = t; f < NB * nc; f += NTHREADS) {
            int b = f / nc, c = f % nc;
            uint4 v = wsA[(size_t)b * 28 + h * 16 + c];
            int off = (b * 256 + c * 16) ^ ((b & 7) << 4);
            *(uint4*)(smem + A_OFF + off) = v;
        }
        for (int f = t; f < EBLK * nc; f += NTHREADS) {
            int e = f / nc, c = f % nc;
            int dg = h * 128 + c * 8;
            uint4 st = {0u, 0u, 0u, 0u};
            if (dg <= DIM - 8) {
                float4 v0 = E4[(size_t)(e0 + e) * D4 + (dg >> 2)];
                float4 v1 = E4[(size_t)(e0 + e) * D4 + (dg >> 2) + 1];
                st.x = packbf(v0.x, v0.y);
                st.y = packbf(v0.z, v0.w);
                st.z = packbf(v1.x, v1.y);
                st.w = packbf(v1.z, v1.w);
            }
            int off = (e * 256 + c * 16) ^ ((e & 7) << 4);
            *(uint4*)(smem + BM_OFF + off) = st;
        }
        __syncthreads();

        const int nst = h ? 3 : 4;
        const int arow = 16 * w + l15;
        const int aswz = (arow & 7) << 4;
        const int bswz = (l15 & 7) << 4;
        #pragma unroll
        for (int s = 0; s < 4; ++s) {
            if (s < nst) {
                int kb = s * 64 + lq * 16;
                bf16x8 af = *(const bf16x8*)(smem + A_OFF + ((arow * 256 + kb) ^ aswz));
                bf16x8 b0 = *(const bf16x8*)(smem + BM_OFF + ((l15 * 256 + kb) ^ bswz));
                bf16x8 b1 = *(const bf16x8*)(smem + BM_OFF + (((16 + l15) * 256 + kb) ^ bswz));
                acc0 = __builtin_amdgcn_mfma_f32_16x16x32_bf16(af, b0, acc0, 0, 0, 0);
                acc1 = __builtin_amdgcn_mfma_f32_16x16x32_bf16(af, b1, acc1, 0, 0, 0);
            }
        }
        __syncthreads();
    }

    // ======== scatter acc via probed coords, gather at r3 map ========
    float* scat = (float*)(smem + SCAT_OFF);
    #pragma unroll
    for (int r = 0; r < 4; ++r) {
        scat[(ib0[r] >> 8) * 33 + (ib0[r] & 255)] = acc0[r];
        scat[(ib1[r] >> 8) * 33 + (ib1[r] & 255)] = acc1[r];
    }
    __syncthreads();

    float2 acc2[4];
    #pragma unroll
    for (int j = 0; j < 4; ++j) {
        acc2[j].x = scat[(2 * ty) * 33 + 4 * tx + j];
        acc2[j].y = scat[(2 * ty + 1) * 33 + 4 * tx + j];
    }
    __syncthreads();

    // ======== stage xsF[100][32] once (conflict-free e-major writes) ========
    const float4* N4 = (const float4*)num_lit;
    float* xsF = (float*)(smem + XS_OFF);
    for (int f = t; f < EBLK * L4; f += NTHREADS) {
        int e = f & 31, l4 = f >> 5;
        float4 v = N4[(size_t)(e0 + e) * L4 + l4];
        const float* vf = (const float*)&v;
        #pragma unroll
        for (int k = 0; k < 4; ++k)
            xsF[(4 * l4 + k) * 32 + e] = vf[k] * sS[4 * l4 + k];
    }
    __syncthreads();   // the ONLY phase-2 barrier

    // ============ phase 2: single loop, asw from global (L2-resident) ============
    const float4* ASW = (const float4*)(ws + WS_ASW);  // [100][32] float4
    #pragma unroll 4
    for (int l = 0; l < NL; ++l) {
        float4 aw = ASW[l * 32 + ty];   // {as[2ty], w[2ty], as[2ty+1], w[2ty+1]}
        float4 xs = *(const float4*)(xsF + l * 32 + 4 * tx);
        float xj[4] = { xs.x, xs.y, xs.z, xs.w };
        #pragma unroll
        for (int j = 0; j < 4; ++j) {
            float m0 = aw.x - xj[j];
            float m1 = aw.z - xj[j];
            float p0 = __builtin_amdgcn_exp2f(-(m0 * m0));
            float p1 = __builtin_amdgcn_exp2f(-(m1 * m1));
            acc2[j].x = fmaf(p0, aw.y, acc2[j].x);
            acc2[j].y = fmaf(p1, aw.w, acc2[j].y);
        }
    }

    // ============ epilogue: sigmoid + float4 stores ============
    {
        float4 o0, o1;
        float* p0 = (float*)&o0;
        float* p1 = (float*)&o1;
        #pragma unroll
        for (int j = 0; j < 4; ++j) {
            float ex0 = __builtin_amdgcn_exp2f(-LOG2E * acc2[j].x);
            float ex1 = __builtin_amdgcn_exp2f(-LOG2E * acc2[j].y);
            p0[j] = __builtin_amdgcn_rcpf(1.0f + ex0);
            p1[j] = __builtin_amdgcn_rcpf(1.0f + ex1);
        }
        size_t b0 = 2 * ty;
        *(float4*)&out[b0 * NE + e0 + 4 * tx] = o0;
        *(float4*)&out[(b0 + 1) * NE + e0 + 4 * tx] = o1;
    }
}

extern "C" void kernel_launch(void* const* d_in, const int* in_sizes, int n_in,
                              void* d_out, int out_size, void* d_ws, size_t ws_size,
                              hipStream_t stream) {
    const int*   e1_idx  = (const int*)d_in[0];
    const int*   r_idx   = (const int*)d_in[1];
    const float* Ew      = (const float*)d_in[2];
    const float* Rw      = (const float*)d_in[3];
    const float* num_lit = (const float*)d_in[4];
    const float* cvec    = (const float*)d_in[5];
    const float* var     = (const float*)d_in[6];
    const float* nfw     = (const float*)d_in[7];
    float* out = (float*)d_out;

    DistMult_prep_kernel<<<8, NTHREADS, 0, stream>>>(
        e1_idx, r_idx, Ew, Rw, num_lit, cvec, var, nfw, (unsigned char*)d_ws);
    DistMult_KBLN_79164837200204_kernel<<<NE / EBLK, NTHREADS, 0, stream>>>(
        Ew, num_lit, var, (const unsigned char*)d_ws, out);
}